// Round 1
// baseline (559.053 us; speedup 1.0000x reference)
//
#include <hip/hip_runtime.h>

#define BT    (128*128)
#define N_    32
#define NQ_   64
#define S_    256
#define O_    128
#define H_    4
#define E_    32
#define HE_   128          // H*E
#define ROWS  8
#define THREADS 256
#define MASK_VALUE -999999.0f

__global__ __launch_bounds__(THREADS) void dqatten_kernel(
    const float* __restrict__ z,      // [BT, N, NQ]
    const float* __restrict__ states, // [BT, S]
    const float* __restrict__ obs,    // [BT, N, O]
    const float* __restrict__ Wq,     // [H*E, S]
    const float* __restrict__ Wk,     // [H*E, O]
    const float* __restrict__ Sb_w1,  // [E, S]
    const float* __restrict__ Sb_b1,  // [E]
    const float* __restrict__ Sb_w2,  // [E]
    const float* __restrict__ Sb_b2,  // [1]
    float* __restrict__ out)          // [BT, NQ]
{
    __shared__ __align__(16) float st[ROWS][S_];     // states
    __shared__ float qv[ROWS][N_];                   // q_vals (z mean)
    __shared__ float qq[ROWS][HE_];                  // q = relu(st @ Wq^T)
    __shared__ __align__(16) float qk[ROWS][H_][O_]; // qk[h,o] = sum_e q[h,e]*Wk[h,e,o]
    __shared__ float sc[ROWS][H_][N_ + 1];           // scores / atten (padded: bank conflicts)
    __shared__ float wn[ROWS][N_];                   // w = sum_h atten
    __shared__ float hb[ROWS][E_];                   // MLP hidden
    __shared__ float vb[ROWS];                       // bias v

    const int tid = threadIdx.x;
    const long row0 = (long)blockIdx.x * ROWS;

    // ---- P0: stage states for 8 rows (fully contiguous) ----
    {
        const float4* sg = (const float4*)(states + row0 * S_);
        float4* sl = (float4*)&st[0][0];
        #pragma unroll
        for (int i = 0; i < (ROWS * S_ / 4) / THREADS; ++i)
            sl[tid + i * THREADS] = sg[tid + i * THREADS];
    }
    // ---- P0b: q_vals[r][n] = mean over nq of z ----
    {
        const int r = tid >> 5, n = tid & 31;   // 8*32 = 256 threads exactly
        const float4* zp = (const float4*)(z + ((row0 + r) * N_ + n) * NQ_);
        float s = 0.f;
        #pragma unroll
        for (int k = 0; k < NQ_ / 4; ++k) {
            float4 v = zp[k];
            s += v.x + v.y + v.z + v.w;
        }
        qv[r][n] = s * (1.0f / NQ_);
    }
    __syncthreads();

    // ---- P1: q[r][he] = relu(st[r] . Wq[he]) ----
    {
        const int he = tid & (HE_ - 1);
        const int rg = tid >> 7;                 // 0..1 -> rows rg*4 .. rg*4+3
        const float4* wq = (const float4*)(Wq + he * S_);
        float acc[4] = {0.f, 0.f, 0.f, 0.f};
        for (int s4 = 0; s4 < S_ / 4; ++s4) {
            float4 w4 = wq[s4];
            #pragma unroll
            for (int j = 0; j < 4; ++j) {
                float4 a = ((const float4*)&st[rg * 4 + j][0])[s4];
                acc[j] += a.x * w4.x + a.y * w4.y + a.z * w4.z + a.w * w4.w;
            }
        }
        #pragma unroll
        for (int j = 0; j < 4; ++j)
            qq[rg * 4 + j][he] = fmaxf(acc[j], 0.f);
    }
    __syncthreads();

    // ---- P2: qk[r][h][o] = sum_e q[r][h*32+e] * Wk[(h*32+e)*128 + o] ----
    {
        const int o = tid & (O_ - 1);
        const int hg = tid >> 7;                 // 0..1
        #pragma unroll
        for (int hh = 0; hh < 2; ++hh) {
            const int h = hg * 2 + hh;
            float acc[ROWS] = {0.f,0.f,0.f,0.f,0.f,0.f,0.f,0.f};
            for (int e = 0; e < E_; ++e) {
                float wv = Wk[(h * E_ + e) * O_ + o];
                #pragma unroll
                for (int r = 0; r < ROWS; ++r)
                    acc[r] += qq[r][h * E_ + e] * wv;
            }
            #pragma unroll
            for (int r = 0; r < ROWS; ++r)
                qk[r][h][o] = acc[r];
        }
    }
    __syncthreads();

    // ---- P3: scores[r][h][n] = scale * obs[r][n] . qk[r][h] (+mask) ----
    {
        const int r = tid >> 5, n = tid & 31;
        const float4* op = (const float4*)(obs + ((row0 + r) * N_ + n) * O_);
        float acc[H_] = {0.f, 0.f, 0.f, 0.f};
        for (int o4 = 0; o4 < O_ / 4; ++o4) {
            float4 ov = op[o4];
            #pragma unroll
            for (int h = 0; h < H_; ++h) {
                float4 kv = ((const float4*)&qk[r][h][0])[o4];
                acc[h] += ov.x * kv.x + ov.y * kv.y + ov.z * kv.z + ov.w * kv.w;
            }
        }
        const float scale = 0.17677669529663687f;  // 1/sqrt(32)
        const bool masked = (qv[r][n] <= MASK_VALUE);
        #pragma unroll
        for (int h = 0; h < H_; ++h)
            sc[r][h][n] = masked ? MASK_VALUE : acc[h] * scale;
    }
    __syncthreads();

    // ---- P4: softmax over n per (r,h) [32 threads]; MLP hidden [all threads] ----
    if (tid < ROWS * H_) {
        const int r = tid >> 2, h = tid & 3;
        float m = -1e30f;
        for (int n = 0; n < N_; ++n) m = fmaxf(m, sc[r][h][n]);
        float ssum = 0.f;
        for (int n = 0; n < N_; ++n) ssum += __expf(sc[r][h][n] - m);
        const float inv = 1.0f / ssum;
        for (int n = 0; n < N_; ++n) sc[r][h][n] = __expf(sc[r][h][n] - m) * inv;
    }
    {
        const int r = tid >> 5, e = tid & 31;
        const float4* w1 = (const float4*)(Sb_w1 + e * S_);
        const float4* sp = (const float4*)&st[r][0];
        float acc = Sb_b1[e];
        for (int s4 = 0; s4 < S_ / 4; ++s4) {
            float4 a = sp[s4];
            float4 w = w1[s4];
            acc += a.x * w.x + a.y * w.y + a.z * w.z + a.w * w.w;
        }
        hb[r][e] = fmaxf(acc, 0.f);
    }
    __syncthreads();

    // ---- P5: w[r][n] = sum_h atten; v[r] = hb . Sb_w2 + b2 ----
    {
        const int r = tid >> 5, n = tid & 31;
        wn[r][n] = sc[r][0][n] + sc[r][1][n] + sc[r][2][n] + sc[r][3][n];
    }
    if (tid < ROWS) {
        float acc = Sb_b2[0];
        for (int e = 0; e < E_; ++e) acc += hb[tid][e] * Sb_w2[e];
        vb[tid] = acc;
    }
    __syncthreads();

    // ---- P6: out[r][nq] = sum_n (w[r][n]+1e-10)*z[r][n][nq] + N*v[r] ----
    {
        const int nq = tid & 63;
        const int rg = tid >> 6;                 // 0..3 -> rows rg, rg+4
        #pragma unroll
        for (int rr = 0; rr < 2; ++rr) {
            const int r = rg + rr * 4;
            const float* zp = z + ((row0 + r) * N_) * NQ_ + nq;
            float acc = 0.f;
            #pragma unroll
            for (int n = 0; n < N_; ++n)
                acc += (wn[r][n] + 1e-10f) * zp[n * NQ_];
            out[(row0 + r) * NQ_ + nq] = acc + (float)N_ * vb[r];
        }
    }
}

extern "C" void kernel_launch(void* const* d_in, const int* in_sizes, int n_in,
                              void* d_out, int out_size, void* d_ws, size_t ws_size,
                              hipStream_t stream) {
    const float* z      = (const float*)d_in[0];
    const float* states = (const float*)d_in[1];
    const float* obs    = (const float*)d_in[2];
    const float* Wq     = (const float*)d_in[3];
    const float* Wk     = (const float*)d_in[4];
    const float* Sb_w1  = (const float*)d_in[5];
    const float* Sb_b1  = (const float*)d_in[6];
    const float* Sb_w2  = (const float*)d_in[7];
    const float* Sb_b2  = (const float*)d_in[8];
    float* out = (float*)d_out;

    dqatten_kernel<<<dim3(BT / ROWS), dim3(THREADS), 0, stream>>>(
        z, states, obs, Wq, Wk, Sb_w1, Sb_b1, Sb_w2, Sb_b2, out);
}